// Round 14
// baseline (721.705 us; speedup 1.0000x reference)
//
#include <hip/hip_runtime.h>

#define DEVFN __device__ __forceinline__

typedef __bf16 bf16x8 __attribute__((ext_vector_type(8)));
typedef float floatx4 __attribute__((ext_vector_type(4)));
typedef unsigned short us4 __attribute__((ext_vector_type(4)));

// ---------- helpers ----------

DEVFN unsigned short f2bf(float x) {
    union { float f; unsigned u; } v; v.f = x;
    v.u += 0x7FFFu + ((v.u >> 16) & 1u);   // RNE
    return (unsigned short)(v.u >> 16);
}

DEVFN float bf2f(unsigned short s) {
    union { unsigned u; float f; } v; v.u = ((unsigned)s) << 16; return v.f;
}

DEVFN float sigm(float x) { return 1.f / (1.f + __expf(-x)); }
DEVFN float tanh_fast(float x) { float t = __expf(2.f * x); return 1.f - 2.f / (t + 1.f); }

DEVFN void gload_lds16(const unsigned short* g, unsigned short* l) {
    __builtin_amdgcn_global_load_lds(
        (__attribute__((address_space(1))) unsigned int*)g,
        (__attribute__((address_space(3))) unsigned int*)l, 16, 0, 0);
}

#define CFENCE asm volatile("" ::: "memory")

// ---------- conversion kernels ----------

__global__ __launch_bounds__(256) void transpose_bt(const float* __restrict__ in,
                                                    unsigned short* __restrict__ out) {
    int idx = blockIdx.x * 256 + threadIdx.x;          // one float4 each
    int k4 = (idx & 255) << 2;
    int row = idx >> 8;                                // t*256 + b
    int t = row >> 8, b = row & 255;
    float4 v = *(const float4*)(in + (size_t)(b * 14 + t) * 1024 + k4);
    us4 o = {f2bf(v.x), f2bf(v.y), f2bf(v.z), f2bf(v.w)};
    *(us4*)(out + (size_t)row * 1024 + k4) = o;
}

__global__ __launch_bounds__(256) void conv_w4(const float* __restrict__ s0, const float* __restrict__ s1,
                                               const float* __restrict__ s2, const float* __restrict__ s3,
                                               unsigned short* __restrict__ d0, unsigned short* __restrict__ d1,
                                               unsigned short* __restrict__ d2, unsigned short* __restrict__ d3) {
    int t = blockIdx.x * 256 + threadIdx.x;
    int which = t >> 20;
    int off = (t & 1048575) << 2;
    const float* s = (which == 0) ? s0 : (which == 1) ? s1 : (which == 2) ? s2 : s3;
    unsigned short* d = (which == 0) ? d0 : (which == 1) ? d1 : (which == 2) ? d2 : d3;
    float4 v = *(const float4*)(s + off);
    us4 o = {f2bf(v.x), f2bf(v.y), f2bf(v.z), f2bf(v.w)};
    *(us4*)(d + off) = o;
}

__global__ __launch_bounds__(256) void conv_cls(const float* __restrict__ in,
                                                unsigned short* __restrict__ out) {
    int t = blockIdx.x * 256 + threadIdx.x;
    int off = t << 2;
    us4 o = {0, 0, 0, 0};
    if (off < 2573312) {
        float4 v = *(const float4*)(in + off);
        o = (us4){f2bf(v.x), f2bf(v.y), f2bf(v.z), f2bf(v.w)};
    }
    *(us4*)(out + off) = o;
}

__global__ __launch_bounds__(256) void bias_interleave(const float* __restrict__ a,
                                                       const float* __restrict__ b,
                                                       float* __restrict__ o4, int n) {
    int i = blockIdx.x * 256 + threadIdx.x;
    if (i < n) {
        int g = i >> 10, h = i & 1023;
        o4[h * 4 + g] = a[i] + b[i];
    }
}

// ===================================================================
// lstm_mega (MODE 2: classifier / MODE 4: dual projection + roll-t0).
// 8-phase 256x256 schedule, 512 thr = 8 waves (2M x 4N), BK=64,
// dbuf LDS 128 KB, counted vmcnt(6) at tile boundaries only.
// ===================================================================
template <int MODE>
__global__ __launch_bounds__(512, 2)
void lstm_mega(const unsigned short* __restrict__ A1,
               const unsigned short* __restrict__ W1,
               const unsigned short* __restrict__ W2,
               const float* __restrict__ bias4a,
               const float* __restrict__ bias4b,
               float* __restrict__ c_out,
               unsigned short* __restrict__ h_out,
               unsigned short* __restrict__ g1,
               unsigned short* __restrict__ g2,
               const float* __restrict__ clsb,
               float* __restrict__ outp) {
    __shared__ __align__(16) unsigned short lds[2][32768];  // [buf][A 16384 | B 16384]

    const int tid = threadIdx.x;
    const int b = blockIdx.x;
    int bx, by;
    if (MODE == 2) {
        bx = b % 10; by = b / 10;
    } else {                         // MODE 4: XCD k owns h-cols [128k,128k+128) of BOTH matrices
        int sel = (b >> 3) & 3;
        bx = ((sel & 1) << 4) + ((b & 7) << 1) + (sel >> 1);
        by = b >> 5;
    }
    const int m0 = by * 256;
    const int n0h = (MODE == 4) ? (bx & 15) * 64 : 0;
    const int n0c = bx * 256;
    const int lane = tid & 63;
    const int wv = tid >> 6;
    const int wm = wv >> 2, wn = wv & 3;
    const int r16 = lane & 15;
    const int kg = lane >> 4;

    const unsigned short* Ws = (MODE == 4 && (bx >> 4)) ? W2 : W1;

    auto st = [&](int t, int s) {
        if (t >= 16) return;
        const int ko = t * 64;
        if (s < 4) {
            int rb = s * 64 + (tid >> 3);
            int kq = tid & 7;
            int kqg = kq ^ (rb & 7);
            int wr;
            if (MODE == 2) wr = n0c + rb;
            else wr = ((rb >> 4) & 3) * 1024 + n0h + ((rb >> 6) << 4) + (rb & 15);
            gload_lds16(Ws + (size_t)wr * 1024 + ko + kqg * 8,
                        &lds[t & 1][16384 + s * 4096 + tid * 8]);
        } else {
            int q = s - 4;
            int lr = tid >> 3;
            int rlog = ((lr >> 5) << 7) + q * 32 + (lr & 31);
            int kq = tid & 7;
            int kqg = kq ^ (lr & 7);
            gload_lds16(A1 + (size_t)(m0 + rlog) * 1024 + ko + kqg * 8,
                        &lds[t & 1][q * 4096 + tid * 8]);
        }
    };

    floatx4 acc[8][4];
#pragma unroll
    for (int i = 0; i < 8; ++i)
#pragma unroll
        for (int j = 0; j < 4; ++j) acc[i][j] = {0.f, 0.f, 0.f, 0.f};

#pragma unroll
    for (int s = 0; s < 8; ++s) st(0, s);
#pragma unroll
    for (int s = 0; s < 6; ++s) st(1, s);
    asm volatile("s_waitcnt vmcnt(6)" ::: "memory");
    __builtin_amdgcn_s_barrier();
    CFENCE;

    for (int v = 0; v < 8; ++v) {
        const int te = 2 * v;
        bf16x8 bfr[4][2];
#pragma unroll
        for (int p = 0; p < 8; ++p) {
            const int q = p & 3;
            const int buf = p >> 2;
            if (p == 0) {
                asm volatile("s_waitcnt vmcnt(6)" ::: "memory");
            } else if (p == 4) {
                if (v == 7) asm volatile("s_waitcnt vmcnt(0)" ::: "memory");
                else        asm volatile("s_waitcnt vmcnt(6)" ::: "memory");
            }
            if (q == 0) {
#pragma unroll
                for (int j = 0; j < 4; ++j)
#pragma unroll
                    for (int kk = 0; kk < 2; ++kk) {
                        int rb = wn * 64 + j * 16 + r16;
                        bfr[j][kk] = *(const bf16x8*)&lds[buf][16384 + rb * 64 +
                                         (((kk << 2) + kg) ^ (rb & 7)) * 8];
                    }
            }
            bf16x8 a[2][2];
#pragma unroll
            for (int i = 0; i < 2; ++i)
#pragma unroll
                for (int kk = 0; kk < 2; ++kk) {
                    int ra = q * 64 + wm * 32 + i * 16 + r16;
                    a[i][kk] = *(const bf16x8*)&lds[buf][ra * 64 +
                                   (((kk << 2) + kg) ^ (ra & 7)) * 8];
                }
            {
                int tt = (p == 0) ? te + 1 : (p <= 4 ? te + 2 : te + 3);
                int s0 = (p == 0 || p == 4) ? 6 : ((p == 1 || p == 5) ? 0 :
                         ((p == 2 || p == 6) ? 2 : 4));
                st(tt, s0);
                st(tt, s0 + 1);
            }
            __builtin_amdgcn_s_barrier();
            CFENCE;
            __builtin_amdgcn_s_setprio(1);
#pragma unroll
            for (int i = 0; i < 2; ++i)
#pragma unroll
                for (int j = 0; j < 4; ++j)
#pragma unroll
                    for (int kk = 0; kk < 2; ++kk)
                        acc[q * 2 + i][j] = __builtin_amdgcn_mfma_f32_16x16x32_bf16(
                            a[i][kk], bfr[j][kk], acc[q * 2 + i][j], 0, 0, 0);
            __builtin_amdgcn_s_setprio(0);
            __builtin_amdgcn_s_barrier();
            CFENCE;
        }
    }

    if (MODE == 2) {
#pragma unroll
        for (int i = 0; i < 8; ++i)
#pragma unroll
            for (int j = 0; j < 4; ++j)
#pragma unroll
                for (int rg = 0; rg < 4; ++rg) {
                    int m = m0 + wm * 128 + i * 16 + kg * 4 + rg;
                    int gn = n0c + wn * 64 + j * 16 + r16;
                    if (gn < 2513) {
                        int bb = m & 255, tt = m >> 8;
                        __builtin_nontemporal_store(acc[i][j][rg] + clsb[gn],
                                                    outp + (size_t)(bb * 14 + tt) * 2513 + gn);
                    }
                }
        return;
    }

    // MODE 4 epilogue
    const int h = n0h + wn * 16 + r16;
    const int half = bx >> 4;
    unsigned short* gsel = half ? g2 : g1;
    const float* bsel = half ? bias4b : bias4a;
    const bool cell0 = (half == 1) && (by == 0);   // roll t=0 rows
    float4 bv = *(const float4*)(bsel + (size_t)h * 4);
#pragma unroll
    for (int i = 0; i < 8; ++i)
#pragma unroll
        for (int rg = 0; rg < 4; ++rg) {
            int m = m0 + wm * 128 + i * 16 + kg * 4 + rg;
            size_t mh = (size_t)m * 1024 + h;
            float gi_ = acc[i][0][rg] + bv.x;
            float gf_ = acc[i][1][rg] + bv.y;
            float gg_ = acc[i][2][rg] + bv.z;
            float go_ = acc[i][3][rg] + bv.w;
            if (cell0) {
                float iv = sigm(gi_), ov = sigm(go_);
                float gv = tanh_fast(gg_);
                float cn = iv * gv;                  // f*0 + i*g
                float hn = ov * tanh_fast(cn);
                c_out[mh] = cn;
                h_out[mh] = f2bf(hn);
            } else {
                us4 o = {f2bf(gi_), f2bf(gf_), f2bf(gg_), f2bf(go_)};
                *(us4*)(gsel + mh * 4) = o;
            }
        }
}

// ===================================================================
// superstep: pipelined roll+unroll. At superstep u (1..15):
//   blocks [0, 16*nbU): unroll step s=u-1-t for branch t=id/16
//     (A = s==0 ? hroll[t] : hp[(u-1)&1][t]; W=uWhh; pre=XpreB[t];
//      c: s==0 reads croll[t], writes cunr[t]; h -> u==15 ? hfinal : hp[u&1])
//   blocks [16*nbU, +16) (u<=13): roll step t=u
//     (A=hroll[u-1], W=rWhh, pre=XrollB[u], croll[u-1]->croll[u], h->hroll[u])
// Same 8-phase 256-row GEMM body as lstm_mega (m0=0, per-block pointers).
// No intra-launch hazards: roll reads/writes croll[u-1]/[u]; unroll reads
// croll[t<=u-1] (read-only) and writes cunr/hp only.
// ===================================================================
__global__ __launch_bounds__(512, 2)
void superstep(unsigned short* __restrict__ hroll,
               const unsigned short* __restrict__ hsrc,
               unsigned short* __restrict__ hdst,
               unsigned short* __restrict__ hfinal,
               float* __restrict__ croll,
               float* __restrict__ cunr,
               const unsigned short* __restrict__ XpreB,
               const unsigned short* __restrict__ XrollB,
               const unsigned short* __restrict__ uWhh,
               const unsigned short* __restrict__ rWhh,
               int u, int nbU) {
    __shared__ __align__(16) unsigned short lds[2][32768];

    const size_t SF = 256 * 1024;
    const int tid = threadIdx.x;
    const int id = blockIdx.x;
    const bool isRoll = (id >= nbU * 16);
    const int rid = isRoll ? id - nbU * 16 : id;
    const int bx = ((rid & 7) << 1) + ((rid >> 3) & 1);   // XCD n-affinity
    const int t = isRoll ? u : (rid >> 4);
    const int s = u - 1 - t;

    const unsigned short* A1;
    const unsigned short* Ws;
    const unsigned short* pre;
    const float* cin;
    float* cout;
    unsigned short* hout;
    bool skipC = false;
    if (isRoll) {
        A1 = hroll + (size_t)(u - 1) * SF;
        Ws = rWhh;
        pre = XrollB + (size_t)u * SF * 4;
        cin = croll + (size_t)(u - 1) * SF;
        cout = croll + (size_t)u * SF;
        hout = hroll + (size_t)u * SF;
    } else {
        A1 = (s == 0 ? hroll : hsrc) + (size_t)t * SF;
        Ws = uWhh;
        pre = XpreB + (size_t)t * SF * 4;
        cin = (s == 0 ? croll : cunr) + (size_t)t * SF;
        cout = cunr + (size_t)t * SF;
        hout = (u == 15 ? hfinal : hdst) + (size_t)t * SF;
        skipC = (u == 15);
    }

    const int n0h = bx * 64;
    const int lane = tid & 63;
    const int wv = tid >> 6;
    const int wm = wv >> 2, wn = wv & 3;
    const int r16 = lane & 15;
    const int kg = lane >> 4;

    auto st = [&](int tt, int ss) {
        if (tt >= 16) return;
        const int ko = tt * 64;
        if (ss < 4) {
            int rb = ss * 64 + (tid >> 3);
            int kq = tid & 7;
            int kqg = kq ^ (rb & 7);
            int wr = ((rb >> 4) & 3) * 1024 + n0h + ((rb >> 6) << 4) + (rb & 15);
            gload_lds16(Ws + (size_t)wr * 1024 + ko + kqg * 8,
                        &lds[tt & 1][16384 + ss * 4096 + tid * 8]);
        } else {
            int q = ss - 4;
            int lr = tid >> 3;
            int rlog = ((lr >> 5) << 7) + q * 32 + (lr & 31);
            int kq = tid & 7;
            int kqg = kq ^ (lr & 7);
            gload_lds16(A1 + (size_t)rlog * 1024 + ko + kqg * 8,
                        &lds[tt & 1][q * 4096 + tid * 8]);
        }
    };

    floatx4 acc[8][4];
#pragma unroll
    for (int i = 0; i < 8; ++i)
#pragma unroll
        for (int j = 0; j < 4; ++j) acc[i][j] = {0.f, 0.f, 0.f, 0.f};

#pragma unroll
    for (int ss = 0; ss < 8; ++ss) st(0, ss);
#pragma unroll
    for (int ss = 0; ss < 6; ++ss) st(1, ss);
    asm volatile("s_waitcnt vmcnt(6)" ::: "memory");
    __builtin_amdgcn_s_barrier();
    CFENCE;

    for (int v = 0; v < 8; ++v) {
        const int te = 2 * v;
        bf16x8 bfr[4][2];
#pragma unroll
        for (int p = 0; p < 8; ++p) {
            const int q = p & 3;
            const int buf = p >> 2;
            if (p == 0) {
                asm volatile("s_waitcnt vmcnt(6)" ::: "memory");
            } else if (p == 4) {
                if (v == 7) asm volatile("s_waitcnt vmcnt(0)" ::: "memory");
                else        asm volatile("s_waitcnt vmcnt(6)" ::: "memory");
            }
            if (q == 0) {
#pragma unroll
                for (int j = 0; j < 4; ++j)
#pragma unroll
                    for (int kk = 0; kk < 2; ++kk) {
                        int rb = wn * 64 + j * 16 + r16;
                        bfr[j][kk] = *(const bf16x8*)&lds[buf][16384 + rb * 64 +
                                         (((kk << 2) + kg) ^ (rb & 7)) * 8];
                    }
            }
            bf16x8 a[2][2];
#pragma unroll
            for (int i = 0; i < 2; ++i)
#pragma unroll
                for (int kk = 0; kk < 2; ++kk) {
                    int ra = q * 64 + wm * 32 + i * 16 + r16;
                    a[i][kk] = *(const bf16x8*)&lds[buf][ra * 64 +
                                   (((kk << 2) + kg) ^ (ra & 7)) * 8];
                }
            {
                int tt = (p == 0) ? te + 1 : (p <= 4 ? te + 2 : te + 3);
                int s0 = (p == 0 || p == 4) ? 6 : ((p == 1 || p == 5) ? 0 :
                         ((p == 2 || p == 6) ? 2 : 4));
                st(tt, s0);
                st(tt, s0 + 1);
            }
            __builtin_amdgcn_s_barrier();
            CFENCE;
            __builtin_amdgcn_s_setprio(1);
#pragma unroll
            for (int i = 0; i < 2; ++i)
#pragma unroll
                for (int j = 0; j < 4; ++j)
#pragma unroll
                    for (int kk = 0; kk < 2; ++kk)
                        acc[q * 2 + i][j] = __builtin_amdgcn_mfma_f32_16x16x32_bf16(
                            a[i][kk], bfr[j][kk], acc[q * 2 + i][j], 0, 0, 0);
            __builtin_amdgcn_s_setprio(0);
            __builtin_amdgcn_s_barrier();
            CFENCE;
        }
    }

    // fused LSTM cell epilogue
    const int h = n0h + wn * 16 + r16;
#pragma unroll
    for (int i = 0; i < 8; ++i)
#pragma unroll
        for (int rg = 0; rg < 4; ++rg) {
            int m = wm * 128 + i * 16 + kg * 4 + rg;
            size_t mh = (size_t)m * 1024 + h;
            us4 pv = *(const us4*)(pre + mh * 4);
            float gi_ = acc[i][0][rg] + bf2f(pv.x);
            float gf_ = acc[i][1][rg] + bf2f(pv.y);
            float gg_ = acc[i][2][rg] + bf2f(pv.z);
            float go_ = acc[i][3][rg] + bf2f(pv.w);
            float co = cin[mh];
            float iv = sigm(gi_), fv = sigm(gf_);
            float gv = tanh_fast(gg_), ov = sigm(go_);
            float cn = fv * co + iv * gv;
            float hn = ov * tanh_fast(cn);
            if (!skipC) cout[mh] = cn;
            hout[mh] = f2bf(hn);
        }
}

// ---------- launch ----------

extern "C" void kernel_launch(void* const* d_in, const int* in_sizes, int n_in,
                              void* d_out, int out_size, void* d_ws, size_t ws_size,
                              hipStream_t stream) {
    (void)in_sizes; (void)n_in; (void)out_size; (void)ws_size;
    const float* inputs   = (const float*)d_in[0];
    const float* roll_Wih = (const float*)d_in[1];
    const float* roll_Whh = (const float*)d_in[2];
    const float* roll_bih = (const float*)d_in[3];
    const float* roll_bhh = (const float*)d_in[4];
    const float* un_Wih   = (const float*)d_in[5];
    const float* un_Whh   = (const float*)d_in[6];
    const float* un_bih   = (const float*)d_in[7];
    const float* un_bhh   = (const float*)d_in[8];
    const float* cls_Wf   = (const float*)d_in[9];
    const float* cls_b    = (const float*)d_in[10];
    float* out = (float*)d_out;

    char* ws = (char*)d_ws;
    size_t off = 0;
    auto alloc = [&](size_t bytes) -> char* {
        char* p = ws + off;
        off += (bytes + 255) & ~(size_t)255;
        return p;
    };
    unsigned short* xt   = (unsigned short*)alloc(3584ull * 1024 * 2);
    unsigned short* rWih = (unsigned short*)alloc(4096ull * 1024 * 2);
    unsigned short* rWhh = (unsigned short*)alloc(4096ull * 1024 * 2);
    unsigned short* uWih = (unsigned short*)alloc(4096ull * 1024 * 2);
    unsigned short* uWhh = (unsigned short*)alloc(4096ull * 1024 * 2);
    unsigned short* cWp  = (unsigned short*)alloc(2560ull * 1024 * 2);
    float* rbias4 = (float*)alloc(1024 * 4 * 4);
    float* ubias4 = (float*)alloc(1024 * 4 * 4);
    unsigned short* XpreB  = (unsigned short*)alloc(3584ull * 4096 * 2);
    unsigned short* XrollB = (unsigned short*)alloc(3584ull * 4096 * 2);
    float* croll = (float*)alloc(3584ull * 1024 * 4);   // roll c chain [t]
    float* cunr  = (float*)alloc(3584ull * 1024 * 4);   // unroll c state [t]
    unsigned short* hroll  = (unsigned short*)alloc(3584ull * 1024 * 2);
    unsigned short* hp0    = (unsigned short*)alloc(3584ull * 1024 * 2);
    unsigned short* hp1    = (unsigned short*)alloc(3584ull * 1024 * 2);
    unsigned short* hfinal = (unsigned short*)alloc(3584ull * 1024 * 2);

    // 1) conversions
    transpose_bt<<<3584, 256, 0, stream>>>(inputs, xt);
    conv_w4<<<16384, 256, 0, stream>>>(roll_Wih, roll_Whh, un_Wih, un_Whh,
                                       rWih, rWhh, uWih, uWhh);
    conv_cls<<<2560, 256, 0, stream>>>(cls_Wf, cWp);
    bias_interleave<<<16, 256, 0, stream>>>(roll_bih, roll_bhh, rbias4, 4096);
    bias_interleave<<<16, 256, 0, stream>>>(un_bih, un_bhh, ubias4, 4096);

    // 2) merged dual projection + roll-t0 cell (8-phase mega, 448 blocks)
    lstm_mega<4><<<448, 512, 0, stream>>>(
        xt, uWih, rWih, ubias4, rbias4,
        croll, hroll, XpreB, XrollB, nullptr, nullptr);

    // 3) pipelined roll + unroll: 15 supersteps
    for (int u = 1; u <= 15; ++u) {
        int nbU = (u < 14) ? u : 14;
        int grid = nbU * 16 + ((u <= 13) ? 16 : 0);
        const unsigned short* hsrc = (u & 1) ? hp1 : hp0;   // hp[(u-1)&1]
        unsigned short* hdst       = (u & 1) ? hp0 : hp1;   // hp[u&1]
        superstep<<<grid, 512, 0, stream>>>(
            hroll, hsrc, hdst, hfinal, croll, cunr,
            XpreB, XrollB, uWhh, rWhh, u, nbU);
    }

    // 4) classifier from hfinal (8-phase mega, grid 14 x 10 = 140)
    lstm_mega<2><<<140, 512, 0, stream>>>(
        hfinal, cWp, nullptr, nullptr, nullptr,
        nullptr, nullptr, nullptr, nullptr, cls_b, out);
}

// Round 15
// 672.985 us; speedup vs baseline: 1.0724x; 1.0724x over previous
//
#include <hip/hip_runtime.h>

#define DEVFN __device__ __forceinline__

typedef __bf16 bf16x8 __attribute__((ext_vector_type(8)));
typedef float floatx4 __attribute__((ext_vector_type(4)));
typedef unsigned short us4 __attribute__((ext_vector_type(4)));

// ---------- helpers ----------

DEVFN unsigned short f2bf(float x) {
    union { float f; unsigned u; } v; v.f = x;
    v.u += 0x7FFFu + ((v.u >> 16) & 1u);   // RNE
    return (unsigned short)(v.u >> 16);
}

DEVFN float bf2f(unsigned short s) {
    union { unsigned u; float f; } v; v.u = ((unsigned)s) << 16; return v.f;
}

DEVFN float sigm(float x) { return 1.f / (1.f + __expf(-x)); }
DEVFN float tanh_fast(float x) { float t = __expf(2.f * x); return 1.f - 2.f / (t + 1.f); }

DEVFN void gload_lds16(const unsigned short* g, unsigned short* l) {
    __builtin_amdgcn_global_load_lds(
        (__attribute__((address_space(1))) unsigned int*)g,
        (__attribute__((address_space(3))) unsigned int*)l, 16, 0, 0);
}

#define CFENCE asm volatile("" ::: "memory")

// ===================================================================
// convert_all: ALL input conversions in one grid-strided launch.
//   seg0 [0, 917504):        inputs [256,14,1024] f32 -> xt [t,b,:] bf16
//   seg1 [917504, 5111808):  4 LSTM weight matrices f32 -> bf16 (x4 vec)
//   seg2 [5111808, 5767168): cls_W -> cWp padded 2560 rows bf16
//   seg3 [5767168, 5775360): biases -> gate-interleaved f32 [h][4]
// ===================================================================
__global__ __launch_bounds__(256)
void convert_all(const float* __restrict__ inputs,
                 const float* __restrict__ rWih_f, const float* __restrict__ rWhh_f,
                 const float* __restrict__ uWih_f, const float* __restrict__ uWhh_f,
                 const float* __restrict__ cls_f,
                 const float* __restrict__ rbih, const float* __restrict__ rbhh,
                 const float* __restrict__ ubih, const float* __restrict__ ubhh,
                 unsigned short* __restrict__ xt,
                 unsigned short* __restrict__ rWih, unsigned short* __restrict__ rWhh,
                 unsigned short* __restrict__ uWih, unsigned short* __restrict__ uWhh,
                 unsigned short* __restrict__ cWp,
                 float* __restrict__ rbias4, float* __restrict__ ubias4) {
    int idx = blockIdx.x * 256 + threadIdx.x;
    if (idx < 917504) {
        // inputs transpose: one float4 per idx
        int k4 = (idx & 255) << 2;
        int row = idx >> 8;                         // t*256 + b
        int t = row >> 8, b = row & 255;
        float4 v = *(const float4*)(inputs + (size_t)(b * 14 + t) * 1024 + k4);
        us4 o = {f2bf(v.x), f2bf(v.y), f2bf(v.z), f2bf(v.w)};
        *(us4*)(xt + (size_t)row * 1024 + k4) = o;
    } else if (idx < 5111808) {
        int j = idx - 917504;
        int which = j >> 20;
        int off = (j & 1048575) << 2;
        const float* s = (which == 0) ? rWih_f : (which == 1) ? rWhh_f
                        : (which == 2) ? uWih_f : uWhh_f;
        unsigned short* d = (which == 0) ? rWih : (which == 1) ? rWhh
                        : (which == 2) ? uWih : uWhh;
        float4 v = *(const float4*)(s + off);
        us4 o = {f2bf(v.x), f2bf(v.y), f2bf(v.z), f2bf(v.w)};
        *(us4*)(d + off) = o;
    } else if (idx < 5767168) {
        int j = idx - 5111808;
        int off = j << 2;
        us4 o = {0, 0, 0, 0};
        if (off < 2573312) {
            float4 v = *(const float4*)(cls_f + off);
            o = (us4){f2bf(v.x), f2bf(v.y), f2bf(v.z), f2bf(v.w)};
        }
        *(us4*)(cWp + off) = o;
    } else {
        int j = idx - 5767168;                      // 0..8191
        int i = j & 4095;
        int g = i >> 10, h = i & 1023;
        if (j < 4096) rbias4[h * 4 + g] = rbih[i] + rbhh[i];
        else          ubias4[h * 4 + g] = ubih[i] + ubhh[i];
    }
}

// ===================================================================
// lstm_mega: 8-phase 256x256 kernel (m201 template port).
// 512 thr = 8 waves (2M x 4N), per-wave out 128 x 64 B-rows, BK=64,
// 16 K-tiles, dbuf LDS 128 KB. Per K-tile: 4 m-quadrant phases, each
// {ds_read subtile; 2 stage-granules; barrier; setprio(1); 16 MFMA;
//  setprio(0); barrier}. vmcnt(6) only at tile boundaries.
// MODE 1: fused LSTM cell (gates gate-gathered; pre4b bf16, c f32)
// MODE 2: classifier (plain B rows, +clsb, remap out[b,t,n])
// MODE 4: dual projection (bx<16: uWih->g1 | bx>=16: rWih->g2),
//         roll-t0 cell folded in (by==0 of roll half -> uc, hb0)
// ===================================================================
template <int MODE>
__global__ __launch_bounds__(512, 2)
void lstm_mega(const unsigned short* __restrict__ A1,
               const unsigned short* __restrict__ W1,
               const unsigned short* __restrict__ W2,
               const unsigned short* __restrict__ pre4b,
               const float* __restrict__ bias4a,
               const float* __restrict__ bias4b,
               const float* __restrict__ c_in,
               float* __restrict__ c_out,
               unsigned short* __restrict__ h_out,
               unsigned short* __restrict__ h_alt, int retire_t,
               unsigned short* __restrict__ g1,
               unsigned short* __restrict__ g2,
               const float* __restrict__ clsb,
               float* __restrict__ outp) {
    __shared__ __align__(16) unsigned short lds[2][32768];  // [buf][A 16384 | B 16384]

    const int tid = threadIdx.x;
    const int b = blockIdx.x;
    int bx, by;
    if (MODE == 2) {                 // one-shot classifier
        bx = b % 10; by = b / 10;
    } else if (MODE == 4) {          // XCD k owns h-cols [128k,128k+128) of BOTH matrices
        int sel = (b >> 3) & 3;
        bx = ((sel & 1) << 4) + ((b & 7) << 1) + (sel >> 1);
        by = b >> 5;
    } else {                         // chain: XCD k owns bx {2k,2k+1}
        bx = ((b & 7) << 1) + ((b >> 3) & 1);
        by = b >> 4;
    }
    const int m0 = by * 256;
    const int n0h = (MODE == 4) ? (bx & 15) * 64 : bx * 64;
    const int n0c = bx * 256;        // MODE 2
    const int lane = tid & 63;
    const int wv = tid >> 6;
    const int wm = wv >> 2, wn = wv & 3;   // 2M x 4N waves
    const int r16 = lane & 15;
    const int kg = lane >> 4;

    const unsigned short* Ws = (MODE == 4 && (bx >> 4)) ? W2 : W1;

    // stage one 8 KB granule (1 issue): s<4 -> B granule s; s>=4 -> A quad s-4
    auto st = [&](int t, int s) {
        if (t >= 16) return;
        const int ko = t * 64;
        if (s < 4) {
            int rb = s * 64 + (tid >> 3);
            int kq = tid & 7;
            int kqg = kq ^ (rb & 7);
            int wr;
            if (MODE == 2) wr = n0c + rb;
            else wr = ((rb >> 4) & 3) * 1024 + n0h + ((rb >> 6) << 4) + (rb & 15);
            gload_lds16(Ws + (size_t)wr * 1024 + ko + kqg * 8,
                        &lds[t & 1][16384 + s * 4096 + tid * 8]);
        } else {
            int q = s - 4;
            int lr = tid >> 3;                               // 0..63
            int rlog = ((lr >> 5) << 7) + q * 32 + (lr & 31);
            int kq = tid & 7;
            int kqg = kq ^ (lr & 7);                         // phys row = q*64+lr, &7 == lr&7
            gload_lds16(A1 + (size_t)(m0 + rlog) * 1024 + ko + kqg * 8,
                        &lds[t & 1][q * 4096 + tid * 8]);
        }
    };

    floatx4 acc[8][4];
#pragma unroll
    for (int i = 0; i < 8; ++i)
#pragma unroll
        for (int j = 0; j < 4; ++j) acc[i][j] = {0.f, 0.f, 0.f, 0.f};

    // prologue: tile0 fully (8 issues) + tile1 granules 0..5 (6 issues)
#pragma unroll
    for (int s = 0; s < 8; ++s) st(0, s);
#pragma unroll
    for (int s = 0; s < 6; ++s) st(1, s);
    asm volatile("s_waitcnt vmcnt(6)" ::: "memory");   // tile0 landed
    __builtin_amdgcn_s_barrier();
    CFENCE;

    for (int v = 0; v < 8; ++v) {
        const int te = 2 * v;
        bf16x8 bfr[4][2];
#pragma unroll
        for (int p = 0; p < 8; ++p) {
            const int q = p & 3;
            const int buf = p >> 2;
            if (p == 0) {
                asm volatile("s_waitcnt vmcnt(6)" ::: "memory");
            } else if (p == 4) {
                if (v == 7) asm volatile("s_waitcnt vmcnt(0)" ::: "memory");
                else        asm volatile("s_waitcnt vmcnt(6)" ::: "memory");
            }
            if (q == 0) {
#pragma unroll
                for (int j = 0; j < 4; ++j)
#pragma unroll
                    for (int kk = 0; kk < 2; ++kk) {
                        int rb = wn * 64 + j * 16 + r16;
                        bfr[j][kk] = *(const bf16x8*)&lds[buf][16384 + rb * 64 +
                                         (((kk << 2) + kg) ^ (rb & 7)) * 8];
                    }
            }
            bf16x8 a[2][2];
#pragma unroll
            for (int i = 0; i < 2; ++i)
#pragma unroll
                for (int kk = 0; kk < 2; ++kk) {
                    int ra = q * 64 + wm * 32 + i * 16 + r16;
                    a[i][kk] = *(const bf16x8*)&lds[buf][ra * 64 +
                                   (((kk << 2) + kg) ^ (ra & 7)) * 8];
                }
            {
                int tt = (p == 0) ? te + 1 : (p <= 4 ? te + 2 : te + 3);
                int s0 = (p == 0 || p == 4) ? 6 : ((p == 1 || p == 5) ? 0 :
                         ((p == 2 || p == 6) ? 2 : 4));
                st(tt, s0);
                st(tt, s0 + 1);
            }
            __builtin_amdgcn_s_barrier();
            CFENCE;
            __builtin_amdgcn_s_setprio(1);
#pragma unroll
            for (int i = 0; i < 2; ++i)
#pragma unroll
                for (int j = 0; j < 4; ++j)
#pragma unroll
                    for (int kk = 0; kk < 2; ++kk)
                        acc[q * 2 + i][j] = __builtin_amdgcn_mfma_f32_16x16x32_bf16(
                            a[i][kk], bfr[j][kk], acc[q * 2 + i][j], 0, 0, 0);
            __builtin_amdgcn_s_setprio(0);
            __builtin_amdgcn_s_barrier();
            CFENCE;
        }
    }

    // ---------- epilogue ----------
    if (MODE == 2) {
#pragma unroll
        for (int i = 0; i < 8; ++i)
#pragma unroll
            for (int j = 0; j < 4; ++j)
#pragma unroll
                for (int rg = 0; rg < 4; ++rg) {
                    int m = m0 + wm * 128 + i * 16 + kg * 4 + rg;
                    int gn = n0c + wn * 64 + j * 16 + r16;
                    if (gn < 2513) {
                        int bb = m & 255, tt = m >> 8;
                        __builtin_nontemporal_store(acc[i][j][rg] + clsb[gn],
                                                    outp + (size_t)(bb * 14 + tt) * 2513 + gn);
                    }
                }
        return;
    }

    const int h = n0h + wn * 16 + r16;

    if (MODE == 4) {
        const int half = bx >> 4;
        unsigned short* gsel = half ? g2 : g1;
        const float* bsel = half ? bias4b : bias4a;
        const bool cell0 = (half == 1) && (by == 0);   // roll t=0 rows (m 0..255)
        float4 bv = *(const float4*)(bsel + (size_t)h * 4);
#pragma unroll
        for (int i = 0; i < 8; ++i)
#pragma unroll
            for (int rg = 0; rg < 4; ++rg) {
                int m = m0 + wm * 128 + i * 16 + kg * 4 + rg;
                size_t mh = (size_t)m * 1024 + h;
                float gi_ = acc[i][0][rg] + bv.x;
                float gf_ = acc[i][1][rg] + bv.y;
                float gg_ = acc[i][2][rg] + bv.z;
                float go_ = acc[i][3][rg] + bv.w;
                if (cell0) {
                    float iv = sigm(gi_), ov = sigm(go_);
                    float gv = tanh_fast(gg_);
                    float cn = iv * gv;                  // f*0 + i*g
                    float hn = ov * tanh_fast(cn);
                    c_out[mh] = cn;
                    h_out[mh] = f2bf(hn);
                } else {
                    us4 o = {f2bf(gi_), f2bf(gf_), f2bf(gg_), f2bf(go_)};
                    *(us4*)(gsel + mh * 4) = o;
                }
            }
        return;
    }

    // MODE 1: fused cell (c f32)
    unsigned short* hw = (by == retire_t) ? h_alt : h_out;
#pragma unroll
    for (int i = 0; i < 8; ++i)
#pragma unroll
        for (int rg = 0; rg < 4; ++rg) {
            int m = m0 + wm * 128 + i * 16 + kg * 4 + rg;
            size_t mh = (size_t)m * 1024 + h;
            us4 pv = *(const us4*)(pre4b + mh * 4);
            float gi_ = acc[i][0][rg] + bf2f(pv.x);
            float gf_ = acc[i][1][rg] + bf2f(pv.y);
            float gg_ = acc[i][2][rg] + bf2f(pv.z);
            float go_ = acc[i][3][rg] + bf2f(pv.w);
            float co = c_in[mh];
            float iv = sigm(gi_), fv = sigm(gf_);
            float gv = tanh_fast(gg_), ov = sigm(go_);
            float cn = fv * co + iv * gv;
            float hn = ov * tanh_fast(cn);
            c_out[mh] = cn;
            hw[mh] = f2bf(hn);
        }
}

// ===================================================================
// lstm_big: BM=128, BK=32, ring-3, NH=32 path for mid-M unroll steps.
// ===================================================================
template <int MODE, int NH>
__global__ __launch_bounds__(256, 2)
void lstm_big(const unsigned short* __restrict__ A1,
              const unsigned short* __restrict__ W1,
              const unsigned short* __restrict__ pre4b,
              const float* __restrict__ c_in,
              float* __restrict__ c_out,
              unsigned short* __restrict__ h_out,
              unsigned short* __restrict__ h_alt, int retire_t, int gx) {
    constexpr int BROWS = 4 * NH;
    constexpr int FN = BROWS / 32;
    constexpr int BISS = BROWS / 64;
    constexpr int LOADS = 2 + BISS;
    constexpr int ASH = 4096;
    constexpr int BSH = BROWS * 32;
    constexpr int HH = NH / 32;

    __shared__ __align__(16) unsigned short lds[3][ASH + BSH];

    const int tid = threadIdx.x;
    const int b = blockIdx.x;
    const int bx = ((b & 7) << 2) + ((b >> 3) & 3);   // NH==32 chain affinity
    const int by = b >> 5;
    const int m0 = by * 128;
    const int n0h = bx * NH;
    const int lane = tid & 63;
    const int wv = tid >> 6;
    const int wm = wv >> 1, wn = wv & 1;
    const int r16 = lane & 15;
    const int kg = lane >> 4;
    (void)gx;

    auto stage = [&](int u, int buf) {
        const int ko = u * 32;
#pragma unroll
        for (int is = 0; is < 2; ++is) {
            int c = is * 256 + tid;
            int row = c >> 2, kq = c & 3;
            int kqg = kq ^ ((row >> 1) & 3);
            gload_lds16(A1 + (size_t)(m0 + row) * 1024 + ko + kqg * 8, &lds[buf][c * 8]);
        }
#pragma unroll
        for (int is = 0; is < BISS; ++is) {
            int c = is * 256 + tid;
            int row = c >> 2, kq = c & 3;
            int kqg = kq ^ ((row >> 1) & 3);
            int wr = ((row >> 4) & 3) * 1024 + n0h + ((row >> 6) << 4) + (row & 15);
            gload_lds16(W1 + (size_t)wr * 1024 + ko + kqg * 8, &lds[buf][ASH + c * 8]);
        }
    };

    floatx4 acc[4][FN];
#pragma unroll
    for (int i = 0; i < 4; ++i)
#pragma unroll
        for (int j = 0; j < FN; ++j) acc[i][j] = {0.f, 0.f, 0.f, 0.f};

    stage(0, 0);
    stage(1, 1);
    stage(2, 2);
    asm volatile("s_waitcnt vmcnt(%0)" :: "n"(2 * LOADS) : "memory");
    __builtin_amdgcn_s_barrier();
    CFENCE;

    int cur = 0;
    for (int u = 0; u < 32; ++u) {
        bf16x8 a[4], bfr[FN];
#pragma unroll
        for (int i = 0; i < 4; ++i) {
            int row = wm * 64 + i * 16 + r16;
            a[i] = *(const bf16x8*)&lds[cur][row * 32 + (kg ^ ((row >> 1) & 3)) * 8];
        }
#pragma unroll
        for (int j = 0; j < FN; ++j) {
            int row = wn * (BROWS / 2) + j * 16 + r16;
            bfr[j] = *(const bf16x8*)&lds[cur][ASH + row * 32 + (kg ^ ((row >> 1) & 3)) * 8];
        }
        __builtin_amdgcn_s_setprio(1);
#pragma unroll
        for (int i = 0; i < 4; ++i)
#pragma unroll
            for (int j = 0; j < FN; ++j)
                acc[i][j] = __builtin_amdgcn_mfma_f32_16x16x32_bf16(a[i], bfr[j], acc[i][j], 0, 0, 0);
        __builtin_amdgcn_s_setprio(0);

        if (u < 31) {
            __builtin_amdgcn_s_barrier();
            if (u < 29) {
                stage(u + 3, cur);
                asm volatile("s_waitcnt vmcnt(%0)" :: "n"(2 * LOADS) : "memory");
            } else if (u == 29) {
                asm volatile("s_waitcnt vmcnt(%0)" :: "n"(LOADS) : "memory");
            } else {
                asm volatile("s_waitcnt vmcnt(0)" ::: "memory");
            }
            __builtin_amdgcn_s_barrier();
            CFENCE;
        }
        cur = (cur == 2) ? 0 : cur + 1;
    }

    unsigned short* hw = ((m0 >> 8) == retire_t) ? h_alt : h_out;
#pragma unroll
    for (int hh = 0; hh < HH; ++hh) {
        const int h = n0h + wn * (NH / 2) + hh * 16 + r16;
#pragma unroll
        for (int i = 0; i < 4; ++i)
#pragma unroll
            for (int rg = 0; rg < 4; ++rg) {
                int m = m0 + wm * 64 + i * 16 + kg * 4 + rg;
                size_t mh = (size_t)m * 1024 + h;
                us4 pv = *(const us4*)(pre4b + mh * 4);
                float gi_ = acc[i][hh * 4 + 0][rg] + bf2f(pv.x);
                float gf_ = acc[i][hh * 4 + 1][rg] + bf2f(pv.y);
                float gg_ = acc[i][hh * 4 + 2][rg] + bf2f(pv.z);
                float go_ = acc[i][hh * 4 + 3][rg] + bf2f(pv.w);
                float co = c_in[mh];
                float iv = sigm(gi_), fv = sigm(gf_);
                float gv = tanh_fast(gg_), ov = sigm(go_);
                float cn = fv * co + iv * gv;
                float hn = ov * tanh_fast(cn);
                c_out[mh] = cn;
                hw[mh] = f2bf(hn);
            }
    }
}

// ===================================================================
// lstm_small: BM=32, BK=64, ring-4, roll chain + small unroll tail.
// ===================================================================
__global__ __launch_bounds__(256)
void lstm_small(const unsigned short* __restrict__ A1, const unsigned short* __restrict__ W1,
                const unsigned short* __restrict__ pre4b,
                const float* __restrict__ c_in,
                float* __restrict__ c_out,
                unsigned short* __restrict__ h_out,
                unsigned short* __restrict__ h_alt, int retire_t) {
    constexpr int ATILE = 32 * 64;
    constexpr int LOADS = 5;

    __shared__ __align__(16) unsigned short lds[4][ATILE + 8192];

    const int tid = threadIdx.x;
    const int b = blockIdx.x;
    const int bx = ((b & 7) << 2) + ((b >> 3) & 3);
    const int by = b >> 5;
    const int m0 = by * 32;
    const int n0 = bx * 32;
    const int lane = tid & 63;
    const int wv = tid >> 6;
    const int wm = wv >> 1, wn = wv & 1;
    const int r16 = lane & 15;
    const int kg = lane >> 4;

    auto stage = [&](int kt, int buf) {
        const int ko = kt * 64;
        {
            int c = tid;
            int row = c >> 3, kq = c & 7, kqg = kq ^ (row & 7);
            gload_lds16(A1 + (size_t)(m0 + row) * 1024 + ko + kqg * 8, &lds[buf][c * 8]);
        }
#pragma unroll
        for (int is = 0; is < 4; ++is) {
            int c = is * 256 + tid;
            int row = c >> 3, kq = c & 7, kqg = kq ^ (row & 7);
            int wr = ((row >> 4) & 3) * 1024 + n0 + ((row >> 6) << 4) + (row & 15);
            gload_lds16(W1 + (size_t)wr * 1024 + ko + kqg * 8, &lds[buf][ATILE + c * 8]);
        }
    };

    floatx4 acc[4];
#pragma unroll
    for (int j = 0; j < 4; ++j) acc[j] = {0.f, 0.f, 0.f, 0.f};

    stage(0, 0);
    stage(1, 1);
    stage(2, 2);
    asm volatile("s_waitcnt vmcnt(%0)" :: "n"(2 * LOADS) : "memory");
    __builtin_amdgcn_s_barrier();
    CFENCE;

#pragma unroll 4
    for (int u = 0; u < 16; ++u) {
        const int cur = u & 3;
#pragma unroll
        for (int kk = 0; kk < 2; ++kk) {
            bf16x8 a, bfr[4];
            const int kqg = kk * 4 + kg;
            {
                int row = wm * 16 + r16;
                a = *(const bf16x8*)&lds[cur][row * 64 + (kqg ^ (row & 7)) * 8];
            }
#pragma unroll
            for (int j = 0; j < 4; ++j) {
                int row = wn * 64 + j * 16 + r16;
                bfr[j] = *(const bf16x8*)&lds[cur][ATILE + row * 64 + (kqg ^ (row & 7)) * 8];
            }
#pragma unroll
            for (int j = 0; j < 4; ++j)
                acc[j] = __builtin_amdgcn_mfma_f32_16x16x32_bf16(a, bfr[j], acc[j], 0, 0, 0);
        }
        if (u < 15) {
            __builtin_amdgcn_s_barrier();
            if (u < 13) {
                stage(u + 3, (u + 3) & 3);
                asm volatile("s_waitcnt vmcnt(%0)" :: "n"(2 * LOADS) : "memory");
            } else if (u == 13) {
                asm volatile("s_waitcnt vmcnt(%0)" :: "n"(LOADS) : "memory");
            } else {
                asm volatile("s_waitcnt vmcnt(0)" ::: "memory");
            }
            __builtin_amdgcn_s_barrier();
            CFENCE;
        }
    }

    const int h = n0 + wn * 16 + r16;
    unsigned short* hw = ((m0 >> 8) == retire_t) ? h_alt : h_out;

#pragma unroll
    for (int rg = 0; rg < 4; ++rg) {
        int m = m0 + wm * 16 + kg * 4 + rg;
        size_t mh = (size_t)m * 1024 + h;
        us4 pv = *(const us4*)(pre4b + mh * 4);
        float gi_ = acc[0][rg] + bf2f(pv.x);
        float gf_ = acc[1][rg] + bf2f(pv.y);
        float gg_ = acc[2][rg] + bf2f(pv.z);
        float go_ = acc[3][rg] + bf2f(pv.w);
        float co = c_in[mh];
        float iv = sigm(gi_), fv = sigm(gf_);
        float gv = tanh_fast(gg_), ov = sigm(go_);
        float cn = fv * co + iv * gv;
        float hn = ov * tanh_fast(cn);
        c_out[mh] = cn;
        hw[mh] = f2bf(hn);
    }
}

// ---------- launch ----------

extern "C" void kernel_launch(void* const* d_in, const int* in_sizes, int n_in,
                              void* d_out, int out_size, void* d_ws, size_t ws_size,
                              hipStream_t stream) {
    (void)in_sizes; (void)n_in; (void)out_size; (void)ws_size;
    const float* inputs   = (const float*)d_in[0];
    const float* roll_Wih = (const float*)d_in[1];
    const float* roll_Whh = (const float*)d_in[2];
    const float* roll_bih = (const float*)d_in[3];
    const float* roll_bhh = (const float*)d_in[4];
    const float* un_Wih   = (const float*)d_in[5];
    const float* un_Whh   = (const float*)d_in[6];
    const float* un_bih   = (const float*)d_in[7];
    const float* un_bhh   = (const float*)d_in[8];
    const float* cls_Wf   = (const float*)d_in[9];
    const float* cls_b    = (const float*)d_in[10];
    float* out = (float*)d_out;

    char* ws = (char*)d_ws;
    size_t off = 0;
    auto alloc = [&](size_t bytes) -> char* {
        char* p = ws + off;
        off += (bytes + 255) & ~(size_t)255;
        return p;
    };
    unsigned short* xt   = (unsigned short*)alloc(3584ull * 1024 * 2);
    unsigned short* rWih = (unsigned short*)alloc(4096ull * 1024 * 2);
    unsigned short* rWhh = (unsigned short*)alloc(4096ull * 1024 * 2);
    unsigned short* uWih = (unsigned short*)alloc(4096ull * 1024 * 2);
    unsigned short* uWhh = (unsigned short*)alloc(4096ull * 1024 * 2);
    unsigned short* cWp  = (unsigned short*)alloc(2560ull * 1024 * 2);
    float* rbias4 = (float*)alloc(1024 * 4 * 4);
    float* ubias4 = (float*)alloc(1024 * 4 * 4);
    unsigned short* XpreB  = (unsigned short*)alloc(3584ull * 4096 * 2);
    unsigned short* XrollB = (unsigned short*)alloc(3584ull * 4096 * 2);
    float* uc     = (float*)alloc(3584ull * 1024 * 4);
    unsigned short* hb0    = (unsigned short*)alloc(3584ull * 1024 * 2);
    unsigned short* hb1    = (unsigned short*)alloc(3584ull * 1024 * 2);
    unsigned short* hfinal = (unsigned short*)alloc(3584ull * 1024 * 2);

    const size_t SF = 256 * 1024;

    // 1) all conversions in one launch (grid covers 5775360 work items)
    convert_all<<<22560, 256, 0, stream>>>(
        inputs, roll_Wih, roll_Whh, un_Wih, un_Whh, cls_Wf,
        roll_bih, roll_bhh, un_bih, un_bhh,
        xt, rWih, rWhh, uWih, uWhh, cWp, rbias4, ubias4);

    // 2) merged dual projection + roll-t0 cell (8-phase mega, 448 blocks)
    lstm_mega<4><<<448, 512, 0, stream>>>(
        xt, uWih, rWih, nullptr, ubias4, rbias4,
        nullptr, uc, hb0, nullptr, -1, XpreB, XrollB, nullptr, nullptr);

    // 3) rolling LSTM t=1..13
    for (int t = 1; t < 14; ++t) {
        lstm_small<<<256, 256, 0, stream>>>(
            hb0 + (size_t)(t - 1) * SF, rWhh,
            XrollB + (size_t)t * SF * 4,
            uc + (size_t)(t - 1) * SF, uc + (size_t)t * SF,
            hb0 + (size_t)t * SF, nullptr, -1);
    }

    // 4) unrolling LSTM: shrinking prefix; retiring branch -> hfinal
    for (int s = 0; s <= 14; ++s) {
        int nb = (15 - s < 14) ? (15 - s) : 14;
        int M = nb * 256;
        const unsigned short* hsrc = (s & 1) ? hb1 : hb0;
        unsigned short* hdst = (s & 1) ? hb0 : hb1;
        int rt = (s >= 1) ? (14 - s) : -1;
        if (M >= 2304) {
            lstm_mega<1><<<nb * 16, 512, 0, stream>>>(
                hsrc, uWhh, nullptr, XpreB, nullptr, nullptr,
                uc, uc, hdst, hfinal, rt, nullptr, nullptr, nullptr, nullptr);
        } else if (M >= 1024) {
            lstm_big<1, 32><<<M / 4, 256, 0, stream>>>(
                hsrc, uWhh, XpreB, uc, uc, hdst, hfinal, rt, 32);
        } else {
            lstm_small<<<M, 256, 0, stream>>>(
                hsrc, uWhh, XpreB, uc, uc, hdst, hfinal, rt);
        }
    }

    // 5) classifier from hfinal (8-phase mega, grid 14 x 10 = 140)
    lstm_mega<2><<<140, 512, 0, stream>>>(
        hfinal, cWp, nullptr, nullptr, nullptr, nullptr,
        nullptr, nullptr, nullptr, nullptr, -1, nullptr, nullptr, cls_b, out);
}